// Round 1
// baseline (395.695 us; speedup 1.0000x reference)
//
#include <hip/hip_runtime.h>

// LatentLinearModel: out[i] = dot(U[users[i]], V[jokes[i]]) + a[users[i]] + b[jokes[i]] + g
// K=64 floats/row = 256 B contiguous. Strategy: 16 lanes per row, float4 per
// lane -> each quarter-wave issues one coalesced 256 B gather per table row.
// Reduction via width-16 shuffles (in-wave on wave64). Memory-bound.

constexpr int KDIM = 64;

__global__ __launch_bounds__(256) void latent_linear_kernel(
    const int* __restrict__ users,
    const int* __restrict__ jokes,
    const float* __restrict__ U,
    const float* __restrict__ V,
    const float* __restrict__ a,
    const float* __restrict__ b,
    const float* __restrict__ g,
    float* __restrict__ out,
    int B)
{
    const int tid = blockIdx.x * blockDim.x + threadIdx.x;
    const int row = tid >> 4;   // 16 lanes per row
    const int sub = tid & 15;   // which float4 of the row
    if (row >= B) return;

    const int ui = users[row];  // same addr across the 16 lanes -> broadcast
    const int ji = jokes[row];

    const float4* __restrict__ U4 = reinterpret_cast<const float4*>(U);
    const float4* __restrict__ V4 = reinterpret_cast<const float4*>(V);

    const float4 uu = U4[(size_t)ui * (KDIM / 4) + sub];
    const float4 vv = V4[(size_t)ji * (KDIM / 4) + sub];

    float dot = uu.x * vv.x + uu.y * vv.y + uu.z * vv.z + uu.w * vv.w;

    // reduce 16 partial sums within each quarter-wave
    dot += __shfl_down(dot, 8, 16);
    dot += __shfl_down(dot, 4, 16);
    dot += __shfl_down(dot, 2, 16);
    dot += __shfl_down(dot, 1, 16);

    if (sub == 0) {
        out[row] = dot + a[ui] + b[ji] + g[0];
    }
}

extern "C" void kernel_launch(void* const* d_in, const int* in_sizes, int n_in,
                              void* d_out, int out_size, void* d_ws, size_t ws_size,
                              hipStream_t stream)
{
    const int*   users = (const int*)d_in[0];
    const int*   jokes = (const int*)d_in[1];
    const float* U     = (const float*)d_in[2];
    const float* V     = (const float*)d_in[3];
    const float* a     = (const float*)d_in[4];
    const float* b     = (const float*)d_in[5];
    const float* g     = (const float*)d_in[6];
    float*       out   = (float*)d_out;

    const int B = in_sizes[0];              // 1048576 rows
    const int threads_total = B * 16;       // 16 lanes per row
    const int block = 256;
    const int grid = (threads_total + block - 1) / block;

    latent_linear_kernel<<<grid, block, 0, stream>>>(users, jokes, U, V, a, b, g, out, B);
}

// Round 2
// 382.793 us; speedup vs baseline: 1.0337x; 1.0337x over previous
//
#include <hip/hip_runtime.h>

// LatentLinearModel: out[i] = dot(U[users[i]], V[jokes[i]]) + a[users[i]] + b[jokes[i]] + g
// K=64 floats/row = 256 B contiguous.
//
// R1 analysis: latency/MLP-bound random gather (caches flushed by harness
// poison fills each iter). Fix: each 16-lane group processes 4 rows per
// visit -> per lane: 1 int4 index load + 8 independent float4 row-gathers
// in flight (4x MLP vs R0). Reduction via width-16 shuffles (in-wave, wave64).

constexpr int KDIM = 64;
constexpr int KV   = KDIM / 4;   // float4s per row = 16
constexpr int RPG  = 4;          // rows per 16-lane group

__global__ __launch_bounds__(256) void latent_linear_kernel(
    const int* __restrict__ users,
    const int* __restrict__ jokes,
    const float* __restrict__ U,
    const float* __restrict__ V,
    const float* __restrict__ a,
    const float* __restrict__ b,
    const float* __restrict__ g,
    float* __restrict__ out,
    int B)
{
    const int tid  = blockIdx.x * blockDim.x + threadIdx.x;
    const int grp  = tid >> 4;          // 16-lane group id
    const int sub  = tid & 15;          // which float4 of a row
    const int base = grp * RPG;
    if (base >= B) return;

    const float4* __restrict__ U4 = reinterpret_cast<const float4*>(U);
    const float4* __restrict__ V4 = reinterpret_cast<const float4*>(V);

    const float g0 = g[0];

    if (base + RPG <= B) {
        // Batch: one int4 load covers this group's 4 user/joke indices
        // (broadcast across the 16 lanes). 16 B aligned: base*4 B = grp*16 B.
        const int4 u4 = reinterpret_cast<const int4*>(users)[grp];
        const int4 j4 = reinterpret_cast<const int4*>(jokes)[grp];
        const int ui[RPG] = {u4.x, u4.y, u4.z, u4.w};
        const int ji[RPG] = {j4.x, j4.y, j4.z, j4.w};

        // 8 independent 16 B gathers per lane -> all in flight together.
        float4 uu[RPG], vv[RPG];
#pragma unroll
        for (int r = 0; r < RPG; ++r) uu[r] = U4[(size_t)ui[r] * KV + sub];
#pragma unroll
        for (int r = 0; r < RPG; ++r) vv[r] = V4[(size_t)ji[r] * KV + sub];

#pragma unroll
        for (int r = 0; r < RPG; ++r) {
            float d = uu[r].x * vv[r].x + uu[r].y * vv[r].y
                    + uu[r].z * vv[r].z + uu[r].w * vv[r].w;
            d += __shfl_down(d, 8, 16);
            d += __shfl_down(d, 4, 16);
            d += __shfl_down(d, 2, 16);
            d += __shfl_down(d, 1, 16);
            if (sub == 0)
                out[base + r] = d + a[ui[r]] + b[ji[r]] + g0;
        }
    } else {
        // tail (not hit for B = 1<<20, kept for generality)
        for (int r = 0; r < RPG && base + r < B; ++r) {
            const int row = base + r;
            const int ui = users[row], ji = jokes[row];
            const float4 uu = U4[(size_t)ui * KV + sub];
            const float4 vv = V4[(size_t)ji * KV + sub];
            float d = uu.x * vv.x + uu.y * vv.y + uu.z * vv.z + uu.w * vv.w;
            d += __shfl_down(d, 8, 16);
            d += __shfl_down(d, 4, 16);
            d += __shfl_down(d, 2, 16);
            d += __shfl_down(d, 1, 16);
            if (sub == 0)
                out[row] = d + a[ui] + b[ji] + g0;
        }
    }
}

extern "C" void kernel_launch(void* const* d_in, const int* in_sizes, int n_in,
                              void* d_out, int out_size, void* d_ws, size_t ws_size,
                              hipStream_t stream)
{
    const int*   users = (const int*)d_in[0];
    const int*   jokes = (const int*)d_in[1];
    const float* U     = (const float*)d_in[2];
    const float* V     = (const float*)d_in[3];
    const float* a     = (const float*)d_in[4];
    const float* b     = (const float*)d_in[5];
    const float* g     = (const float*)d_in[6];
    float*       out   = (float*)d_out;

    const int B = in_sizes[0];                        // 1048576 rows
    const int groups = (B + RPG - 1) / RPG;           // 16-lane groups
    const long long threads_total = (long long)groups * 16;
    const int block = 256;
    const int grid = (int)((threads_total + block - 1) / block);

    latent_linear_kernel<<<grid, block, 0, stream>>>(users, jokes, U, V, a, b, g, out, B);
}